// Round 9
// baseline (365.779 us; speedup 1.0000x reference)
//
#include <hip/hip_runtime.h>
#include <math.h>

#define NB 32
#define NL 4096
#define ND 1024
#define NK 64
#define DTILE 128
#define S_SPLIT 4

typedef __bf16 bf16_t;
typedef __bf16 bf16x8 __attribute__((ext_vector_type(8)));
typedef __bf16 bf16x4 __attribute__((ext_vector_type(4)));
typedef float f32x4_t __attribute__((ext_vector_type(4)));

// ---------------- Kernel 0: W fp32 -> bf16
__global__ __launch_bounds__(256) void k_convw(const float* __restrict__ W,
                                               bf16_t* __restrict__ Wb) {
    const int i = (blockIdx.x * 256 + threadIdx.x) * 4;
    const float4 v = *(const float4*)(W + i);
    bf16x4 o;
    o[0] = (bf16_t)v.x; o[1] = (bf16_t)v.y; o[2] = (bf16_t)v.z; o[3] = (bf16_t)v.w;
    *(bf16x4*)(Wb + i) = o;
}

// ---------------- Kernel 1: logits (bf16 MFMA), 64 l per wave, 256 l per block
// Also writes fbf = bf16(feats) (the af fragments, 16B coalesced stores).
// Verified conv: A lane(lr,oct): m=lr, c=oct*8+j; B: n=lr, c=oct*8+j;
// C: col(n)=lane&15, row(m)=oct*4+reg.
__global__ __launch_bounds__(256, 2) void k_logits(const float* __restrict__ feats,
                                                   const bf16_t* __restrict__ Wb,
                                                   const float* __restrict__ bias,
                                                   const int* __restrict__ lens,
                                                   float* __restrict__ logitsT,
                                                   bf16_t* __restrict__ fbf,
                                                   float* __restrict__ pmax,
                                                   float* __restrict__ psum) {
    const int bid = blockIdx.x;
    const int b = bid >> 4;
    const int chunk = bid & 15;
    const int l0 = chunk << 8;       // 256 l per block
    const int len = lens[b];
    if (l0 >= len) return;   // rows >= len never read downstream
    const int t = threadIdx.x;
    const int w = t >> 6;
    const int lane = t & 63;
    const int lr = lane & 15;
    const int oct = lane >> 4;
    const int lw = l0 + w * 64;      // wave's l-base (4 m-tiles of 16)
    const float* fp = feats + ((size_t)b * NL + lw + lr) * ND + oct * 8;
    bf16_t* fq = fbf + ((size_t)b * NL + lw + lr) * ND + oct * 8;

    f32x4_t acc[4][4];  // [mt][j]
#pragma unroll
    for (int m = 0; m < 4; ++m)
#pragma unroll
        for (int j = 0; j < 4; ++j) acc[m][j] = (f32x4_t){0.f, 0.f, 0.f, 0.f};

#pragma unroll 2
    for (int kk = 0; kk < 32; ++kk) {
        const int d = kk * 32;
        bf16x8 af[4];
#pragma unroll
        for (int mt = 0; mt < 4; ++mt) {
            const float4 a0 = *(const float4*)(fp + (size_t)mt * 16 * ND + d);
            const float4 a1 = *(const float4*)(fp + (size_t)mt * 16 * ND + d + 4);
            af[mt][0] = (bf16_t)a0.x; af[mt][1] = (bf16_t)a0.y;
            af[mt][2] = (bf16_t)a0.z; af[mt][3] = (bf16_t)a0.w;
            af[mt][4] = (bf16_t)a1.x; af[mt][5] = (bf16_t)a1.y;
            af[mt][6] = (bf16_t)a1.z; af[mt][7] = (bf16_t)a1.w;
            *(bf16x8*)(fq + (size_t)mt * 16 * ND + d) = af[mt];
        }
#pragma unroll
        for (int j = 0; j < 4; ++j) {
            const bf16x8 bf = *(const bf16x8*)(Wb + (size_t)(j * 16 + lr) * ND + d + oct * 8);
#pragma unroll
            for (int mt = 0; mt < 4; ++mt)
                acc[mt][j] = __builtin_amdgcn_mfma_f32_16x16x32_bf16(af[mt], bf, acc[mt][j], 0, 0, 0);
        }
    }
    float vals[4][4][4];
#pragma unroll
    for (int mt = 0; mt < 4; ++mt)
#pragma unroll
        for (int j = 0; j < 4; ++j) {
            const int k = j * 16 + lr;
            const float bs = bias[k];
#pragma unroll
            for (int r = 0; r < 4; ++r) vals[mt][j][r] = acc[mt][j][r] + bs;
            const int lb = lw + mt * 16 + oct * 4;
            float4 st = make_float4(vals[mt][j][0], vals[mt][j][1], vals[mt][j][2], vals[mt][j][3]);
            *(float4*)(logitsT + ((size_t)b * NK + k) * NL + lb) = st;
        }
    // fused partial softmax stats for this 256-l chunk (16 slots per k)
    __shared__ float red[64][17];
    __shared__ float bm[64];
    const int slot = w * 4 + oct;
#pragma unroll
    for (int j = 0; j < 4; ++j) {
        float vm = -1e30f;
#pragma unroll
        for (int mt = 0; mt < 4; ++mt) {
            const int lbase = lw + mt * 16 + oct * 4;
#pragma unroll
            for (int r = 0; r < 4; ++r)
                if (lbase + r < len) vm = fmaxf(vm, vals[mt][j][r]);
        }
        red[j * 16 + lr][slot] = vm;
    }
    __syncthreads();
    if (t < 64) {
        float m = -1e30f;
#pragma unroll
        for (int q = 0; q < 16; ++q) m = fmaxf(m, red[t][q]);
        bm[t] = m;
    }
    __syncthreads();
#pragma unroll
    for (int j = 0; j < 4; ++j) {
        const float mk = bm[j * 16 + lr];
        float sj = 0.f;
#pragma unroll
        for (int mt = 0; mt < 4; ++mt) {
            const int lbase = lw + mt * 16 + oct * 4;
#pragma unroll
            for (int r = 0; r < 4; ++r)
                if (lbase + r < len) sj += __expf(vals[mt][j][r] - mk);
        }
        red[j * 16 + lr][slot] = sj;
    }
    __syncthreads();
    if (t < 64) {
        float ssum = 0.f;
#pragma unroll
        for (int q = 0; q < 16; ++q) ssum += red[t][q];
        pmax[((size_t)b * 16 + chunk) * 64 + t] = bm[t];
        psum[((size_t)b * 16 + chunk) * 64 + t] = ssum;
    }
}

// ---------------- Kernel 2: combine chunk stats -> mbuf2 = m + ln(s) per (b,k)
__global__ void k_sm2(const float* __restrict__ pmax, const float* __restrict__ psum,
                      const int* __restrict__ lens,
                      float* __restrict__ mbuf2) {
    const int b = blockIdx.x;
    const int k = threadIdx.x;  // 64 threads
    const int nc = (lens[b] + 255) >> 8;
    float m = -1e30f;
    for (int c = 0; c < nc; ++c) m = fmaxf(m, pmax[((size_t)b * 16 + c) * 64 + k]);
    float s = 0.f;
    for (int c = 0; c < nc; ++c)
        s += psum[((size_t)b * 16 + c) * 64 + k] * __expf(pmax[((size_t)b * 16 + c) * 64 + k] - m);
    mbuf2[b * 64 + k] = m + logf(s);
}

// ---------------- Kernel 3: bf16-MFMA aggregation (exact-a x bf16-f)
// f read as pre-rounded bf16 (fbf) -> half the load bytes/instructions, no cvt.
// Wave partition: (kh = w&1: 32 k) x (dh = w>>1: 64 d).
__global__ __launch_bounds__(256, 3) void k_aggregate(const bf16_t* __restrict__ fbf,
                                                      const float* __restrict__ logitsT,
                                                      const int* __restrict__ lens,
                                                      const float* __restrict__ mbuf2,
                                                      float* __restrict__ pO) {
    const int bid = blockIdx.x;
    const int s  = bid & 3;
    const int dc = (bid >> 2) & 7;
    const int b  = bid >> 5;
    const int d0 = dc * DTILE;
    const int t = threadIdx.x;
    const int kh = (t >> 6) & 1;
    const int dh = t >> 7;
    const int lane = t & 63;
    const int lr = lane & 15;
    const int oct = lane >> 4;
    const int len = lens[b];
    const int nT = (len + 63) >> 6;
    const int t0 = (nT * s) >> 2;
    const int t1 = (nT * (s + 1)) >> 2;

    __shared__ char fH[16 * 1024];   // fT[128 d][64 l] bf16, chunk-XOR swizzled

    const int kk0 = kh * 32 + lr;    // A m-row (k) for mt=0; mt=1 adds 16
    const float ms0 = mbuf2[b * 64 + kk0];
    const float ms1 = mbuf2[b * 64 + kk0 + 16];
    const float* lg0 = logitsT + ((size_t)b * NK + kk0) * NL;
    const float* lg1 = lg0 + (size_t)16 * NL;

    // f-staging constants: thread owns rows lf0+{0..3}, cols c8..c8+7 (bf16)
    const int c8 = (t & 15) * 8;
    const int lf0 = (t >> 4) * 4;

    f32x4_t acc[2][4];  // [mt][n]
#pragma unroll
    for (int m = 0; m < 2; ++m)
#pragma unroll
        for (int n = 0; n < 4; ++n) acc[m][n] = (f32x4_t){0.f, 0.f, 0.f, 0.f};

    bf16x8 pfb[4];     // prefetched f rows (T14)

#define LOADF(tile_)                                                                     \
    {                                                                                    \
        const int lb_ = (tile_) * 64;                                                    \
        _Pragma("unroll")                                                                \
        for (int i_ = 0; i_ < 4; ++i_)                                                   \
            pfb[i_] = *(const bf16x8*)(fbf +                                             \
                ((size_t)b * NL + lb_ + lf0 + i_) * ND + d0 + c8);                       \
    }

    if (t0 < t1) LOADF(t0);

    for (int tile = t0; tile < t1; ++tile) {
        const int l0 = tile * 64;
        // ---- load this tile's logits runs + build A fragments in registers
        bf16x8 afH[2][2], afL[2][2];   // [mt][ks]
#pragma unroll
        for (int mt = 0; mt < 2; ++mt) {
            const float* lg = mt ? lg1 : lg0;
            const float msk = mt ? ms1 : ms0;
            float4 g[4];
            g[0] = *(const float4*)(lg + l0 + oct * 8);
            g[1] = *(const float4*)(lg + l0 + oct * 8 + 4);
            g[2] = *(const float4*)(lg + l0 + 32 + oct * 8);
            g[3] = *(const float4*)(lg + l0 + 32 + oct * 8 + 4);
#pragma unroll
            for (int ks = 0; ks < 2; ++ks) {
#pragma unroll
                for (int h = 0; h < 2; ++h) {
                    const float4 v = g[ks * 2 + h];
                    const int lbase = l0 + ks * 32 + oct * 8 + h * 4;
                    float av[4];
                    av[0] = (lbase + 0 < len) ? __expf(v.x - msk) : 0.f;
                    av[1] = (lbase + 1 < len) ? __expf(v.y - msk) : 0.f;
                    av[2] = (lbase + 2 < len) ? __expf(v.z - msk) : 0.f;
                    av[3] = (lbase + 3 < len) ? __expf(v.w - msk) : 0.f;
#pragma unroll
                    for (int c = 0; c < 4; ++c) {
                        const bf16_t hi = (bf16_t)av[c];
                        afH[mt][ks][h * 4 + c] = hi;
                        afL[mt][ks][h * 4 + c] = (bf16_t)(av[c] - (float)hi);
                    }
                }
            }
        }
        __syncthreads();   // all waves done reading fH of previous tile
        // ---- stage f^T (already bf16): pure 4x8 register micro-transpose
#pragma unroll
        for (int j = 0; j < 8; ++j) {
            const int d = c8 + j;
            bf16x4 hi;
            hi[0] = pfb[0][j]; hi[1] = pfb[1][j]; hi[2] = pfb[2][j]; hi[3] = pfb[3][j];
            const int chunk = (lf0 >> 3) ^ ((d ^ (d >> 3)) & 7);
            const int off = d * 128 + (chunk << 4) + (lf0 & 7) * 2;
            *(bf16x4*)(fH + off) = hi;
        }
        // ---- T14: issue next tile's f loads (in flight across barrier + MFMA)
        if (tile + 1 < t1) LOADF(tile + 1);
        __syncthreads();   // fH ready
        // ---- MFMA: wave owns k in [kh*32, +32), d in [dh*64, +64)
#pragma unroll
        for (int ks = 0; ks < 2; ++ks) {
            const int cbase = ks * 4 + oct;  // chunk of contraction l = ks*32 + oct*8
            bf16x8 bfv[4];
#pragma unroll
            for (int n = 0; n < 4; ++n) {
                const int d = dh * 64 + n * 16 + lr;
                const int foff = d * 128 + ((cbase ^ ((d ^ (d >> 3)) & 7)) << 4);
                bfv[n] = *(const bf16x8*)(fH + foff);
            }
#pragma unroll
            for (int mt = 0; mt < 2; ++mt)
#pragma unroll
                for (int n = 0; n < 4; ++n) {
                    acc[mt][n] = __builtin_amdgcn_mfma_f32_16x16x32_bf16(afH[mt][ks], bfv[n], acc[mt][n], 0, 0, 0);
                    acc[mt][n] = __builtin_amdgcn_mfma_f32_16x16x32_bf16(afL[mt][ks], bfv[n], acc[mt][n], 0, 0, 0);
                }
        }
    }
#undef LOADF
    // write fp32 partials: pO[b][dc][s][k][DTILE]; C: row(m=k)=oct*4+r, col=lr
    float* po = pO + ((size_t)((b * 8 + dc) * S_SPLIT + s)) * (NK * DTILE);
#pragma unroll
    for (int mt = 0; mt < 2; ++mt)
#pragma unroll
        for (int n = 0; n < 4; ++n) {
#pragma unroll
            for (int r = 0; r < 4; ++r) {
                const int k = kh * 32 + mt * 16 + oct * 4 + r;
                po[k * DTILE + dh * 64 + n * 16 + lr] = acc[mt][n][r];
            }
        }
}

// ---------------- Kernel 4: sum S_SPLIT partials, subtract centroid, min over k
__global__ __launch_bounds__(128) void k_combine(const float* __restrict__ pO,
                                                 const float* __restrict__ centroids,
                                                 float* __restrict__ outun) {
    const int b = blockIdx.x >> 3;
    const int d = (blockIdx.x & 7) * 128 + threadIdx.x;  // 0..1023
    const int dc = d >> 7;
    const int dl = d & 127;
    const float* base = pO + ((size_t)(b * 8 + dc)) * S_SPLIT * NK * DTILE;
    float mn = 1e30f;
    for (int k = 0; k < NK; ++k) {
        float v = 0.f;
#pragma unroll
        for (int s = 0; s < S_SPLIT; ++s) v += base[(size_t)(s * NK + k) * DTILE + dl];
        v -= centroids[(size_t)k * ND + d];
        mn = fminf(mn, v);
    }
    outun[(size_t)b * ND + d] = mn;
}

// ---------------- Kernel 5: L2-normalize rows
__global__ __launch_bounds__(256) void k_norm(const float* __restrict__ outun,
                                              float* __restrict__ out) {
    const int b = blockIdx.x;
    const int t = threadIdx.x;
    float ss = 0.f;
    for (int d = t; d < ND; d += 256) {
        const float v = outun[(size_t)b * ND + d];
        ss += v * v;
    }
#pragma unroll
    for (int off = 32; off > 0; off >>= 1) ss += __shfl_down(ss, off);
    __shared__ float red[4];
    if ((t & 63) == 0) red[t >> 6] = ss;
    __syncthreads();
    const float tot = red[0] + red[1] + red[2] + red[3];
    const float inv = 1.0f / fmaxf(sqrtf(tot), 1e-12f);
    for (int d = t; d < ND; d += 256) out[(size_t)b * ND + d] = outun[(size_t)b * ND + d] * inv;
}

extern "C" void kernel_launch(void* const* d_in, const int* in_sizes, int n_in,
                              void* d_out, int out_size, void* d_ws, size_t ws_size,
                              hipStream_t stream) {
    const float* feats     = (const float*)d_in[0];
    const int*   lens      = (const int*)d_in[1];
    const float* W         = (const float*)d_in[2];
    const float* bias      = (const float*)d_in[3];
    const float* centroids = (const float*)d_in[4];
    float* out = (float*)d_out;

    char* ws = (char*)d_ws;
    size_t off = 0;
    bf16_t* Wb     = (bf16_t*)(ws + off); off += (size_t)NK * ND * sizeof(bf16_t);
    bf16_t* fbf    = (bf16_t*)(ws + off); off += (size_t)NB * NL * ND * sizeof(bf16_t); // 256 MB
    float* logitsT = (float*)(ws + off);  off += (size_t)NB * NL * NK * sizeof(float);
    float* pmax    = (float*)(ws + off);  off += (size_t)NB * 16 * NK * sizeof(float);
    float* psum    = (float*)(ws + off);  off += (size_t)NB * 16 * NK * sizeof(float);
    float* mbuf2   = (float*)(ws + off);  off += (size_t)NB * NK * sizeof(float);
    float* outun   = (float*)(ws + off);  off += (size_t)NB * ND * sizeof(float);
    float* pO      = (float*)(ws + off);  // 32*8*4*64*128*4 = 33.6 MB

    k_convw<<<NK * ND / 1024, 256, 0, stream>>>(W, Wb);
    k_logits<<<NB * (NL / 256), 256, 0, stream>>>(feats, Wb, bias, lens, logitsT, fbf, pmax, psum);
    k_sm2<<<NB, 64, 0, stream>>>(pmax, psum, lens, mbuf2);
    k_aggregate<<<NB * 8 * S_SPLIT, 256, 0, stream>>>(fbf, logitsT, lens, mbuf2, pO);
    k_combine<<<NB * 8, 128, 0, stream>>>(pO, centroids, outun);
    k_norm<<<NB, 256, 0, stream>>>(outun, out);
}

// Round 10
// 287.479 us; speedup vs baseline: 1.2724x; 1.2724x over previous
//
#include <hip/hip_runtime.h>
#include <math.h>

#define NB 32
#define NL 4096
#define ND 1024
#define NK 64
#define DTILE 256
#define S_SPLIT 4

typedef __bf16 bf16_t;
typedef __bf16 bf16x8 __attribute__((ext_vector_type(8)));
typedef __bf16 bf16x4 __attribute__((ext_vector_type(4)));
typedef float f32x4_t __attribute__((ext_vector_type(4)));

// ---------------- Kernel 0: W fp32 -> bf16
__global__ __launch_bounds__(256) void k_convw(const float* __restrict__ W,
                                               bf16_t* __restrict__ Wb) {
    const int i = (blockIdx.x * 256 + threadIdx.x) * 4;
    const float4 v = *(const float4*)(W + i);
    bf16x4 o;
    o[0] = (bf16_t)v.x; o[1] = (bf16_t)v.y; o[2] = (bf16_t)v.z; o[3] = (bf16_t)v.w;
    *(bf16x4*)(Wb + i) = o;
}

// ---------------- Kernel 1: logits (bf16 MFMA), 64 l per wave, 256 l per block
// (round-8 proven form). Writes logitsT[b][k][l]; fused per-chunk softmax stats.
__global__ __launch_bounds__(256, 2) void k_logits(const float* __restrict__ feats,
                                                   const bf16_t* __restrict__ Wb,
                                                   const float* __restrict__ bias,
                                                   const int* __restrict__ lens,
                                                   float* __restrict__ logitsT,
                                                   float* __restrict__ pmax,
                                                   float* __restrict__ psum) {
    const int bid = blockIdx.x;
    const int b = bid >> 4;
    const int chunk = bid & 15;
    const int l0 = chunk << 8;       // 256 l per block
    const int len = lens[b];
    if (l0 >= len) return;   // rows >= len never read downstream
    const int t = threadIdx.x;
    const int w = t >> 6;
    const int lane = t & 63;
    const int lr = lane & 15;
    const int oct = lane >> 4;
    const int lw = l0 + w * 64;      // wave's l-base (4 m-tiles of 16)
    const float* fp = feats + ((size_t)b * NL + lw + lr) * ND + oct * 8;

    f32x4_t acc[4][4];  // [mt][j]
#pragma unroll
    for (int m = 0; m < 4; ++m)
#pragma unroll
        for (int j = 0; j < 4; ++j) acc[m][j] = (f32x4_t){0.f, 0.f, 0.f, 0.f};

#pragma unroll 2
    for (int kk = 0; kk < 32; ++kk) {
        const int d = kk * 32;
        bf16x8 af[4];
#pragma unroll
        for (int mt = 0; mt < 4; ++mt) {
            const float4 a0 = *(const float4*)(fp + (size_t)mt * 16 * ND + d);
            const float4 a1 = *(const float4*)(fp + (size_t)mt * 16 * ND + d + 4);
            af[mt][0] = (bf16_t)a0.x; af[mt][1] = (bf16_t)a0.y;
            af[mt][2] = (bf16_t)a0.z; af[mt][3] = (bf16_t)a0.w;
            af[mt][4] = (bf16_t)a1.x; af[mt][5] = (bf16_t)a1.y;
            af[mt][6] = (bf16_t)a1.z; af[mt][7] = (bf16_t)a1.w;
        }
#pragma unroll
        for (int j = 0; j < 4; ++j) {
            const bf16x8 bf = *(const bf16x8*)(Wb + (size_t)(j * 16 + lr) * ND + d + oct * 8);
#pragma unroll
            for (int mt = 0; mt < 4; ++mt)
                acc[mt][j] = __builtin_amdgcn_mfma_f32_16x16x32_bf16(af[mt], bf, acc[mt][j], 0, 0, 0);
        }
    }
    float vals[4][4][4];
#pragma unroll
    for (int mt = 0; mt < 4; ++mt)
#pragma unroll
        for (int j = 0; j < 4; ++j) {
            const int k = j * 16 + lr;
            const float bs = bias[k];
#pragma unroll
            for (int r = 0; r < 4; ++r) vals[mt][j][r] = acc[mt][j][r] + bs;
            const int lb = lw + mt * 16 + oct * 4;
            float4 st = make_float4(vals[mt][j][0], vals[mt][j][1], vals[mt][j][2], vals[mt][j][3]);
            *(float4*)(logitsT + ((size_t)b * NK + k) * NL + lb) = st;
        }
    // fused partial softmax stats for this 256-l chunk (16 slots per k)
    __shared__ float red[64][17];
    __shared__ float bm[64];
    const int slot = w * 4 + oct;
#pragma unroll
    for (int j = 0; j < 4; ++j) {
        float vm = -1e30f;
#pragma unroll
        for (int mt = 0; mt < 4; ++mt) {
            const int lbase = lw + mt * 16 + oct * 4;
#pragma unroll
            for (int r = 0; r < 4; ++r)
                if (lbase + r < len) vm = fmaxf(vm, vals[mt][j][r]);
        }
        red[j * 16 + lr][slot] = vm;
    }
    __syncthreads();
    if (t < 64) {
        float m = -1e30f;
#pragma unroll
        for (int q = 0; q < 16; ++q) m = fmaxf(m, red[t][q]);
        bm[t] = m;
    }
    __syncthreads();
#pragma unroll
    for (int j = 0; j < 4; ++j) {
        const float mk = bm[j * 16 + lr];
        float sj = 0.f;
#pragma unroll
        for (int mt = 0; mt < 4; ++mt) {
            const int lbase = lw + mt * 16 + oct * 4;
#pragma unroll
            for (int r = 0; r < 4; ++r)
                if (lbase + r < len) sj += __expf(vals[mt][j][r] - mk);
        }
        red[j * 16 + lr][slot] = sj;
    }
    __syncthreads();
    if (t < 64) {
        float ssum = 0.f;
#pragma unroll
        for (int q = 0; q < 16; ++q) ssum += red[t][q];
        pmax[((size_t)b * 16 + chunk) * 64 + t] = bm[t];
        psum[((size_t)b * 16 + chunk) * 64 + t] = ssum;
    }
}

// ---------------- Kernel 2: combine chunk stats -> mbuf2 = m + ln(s) per (b,k)
__global__ void k_sm2(const float* __restrict__ pmax, const float* __restrict__ psum,
                      const int* __restrict__ lens,
                      float* __restrict__ mbuf2) {
    const int b = blockIdx.x;
    const int k = threadIdx.x;  // 64 threads
    const int nc = (lens[b] + 255) >> 8;
    float m = -1e30f;
    for (int c = 0; c < nc; ++c) m = fmaxf(m, pmax[((size_t)b * 16 + c) * 64 + k]);
    float s = 0.f;
    for (int c = 0; c < nc; ++c)
        s += psum[((size_t)b * 16 + c) * 64 + k] * __expf(pmax[((size_t)b * 16 + c) * 64 + k] - m);
    mbuf2[b * 64 + k] = m + logf(s);
}

// ---------------- Kernel 3: bf16-MFMA aggregation (exact-a x bf16-f)
// 512 thr / 8 waves: (kh = w&1: 32 k) x (dh = w>>1: 64 d), DTILE=256.
// Both logits (plg) and feats (pf) prefetched one tile ahead (T14).
__global__ __launch_bounds__(512, 2) void k_aggregate(const float* __restrict__ feats,
                                                      const float* __restrict__ logitsT,
                                                      const int* __restrict__ lens,
                                                      const float* __restrict__ mbuf2,
                                                      float* __restrict__ pO) {
    const int bid = blockIdx.x;
    const int s  = bid & 3;
    const int dc = (bid >> 2) & 3;
    const int b  = bid >> 4;
    const int d0 = dc * DTILE;
    const int t = threadIdx.x;
    const int w = t >> 6;
    const int kh = w & 1;
    const int dh = w >> 1;
    const int lane = t & 63;
    const int lr = lane & 15;
    const int oct = lane >> 4;
    const int len = lens[b];
    const int nT = (len + 63) >> 6;
    const int t0 = (nT * s) >> 2;
    const int t1 = (nT * (s + 1)) >> 2;

    __shared__ char fH[32 * 1024];   // fT[256 d][64 l] bf16, chunk-XOR swizzled

    const int kk0 = kh * 32 + lr;    // A m-row (k) for mt=0; mt=1 adds 16
    const float ms0 = mbuf2[b * 64 + kk0];
    const float ms1 = mbuf2[b * 64 + kk0 + 16];
    const float* lg0 = logitsT + ((size_t)b * NK + kk0) * NL;
    const float* lg1 = lg0 + (size_t)16 * NL;

    // f-staging constants: wave w owns rows w*8..w*8+7 (2 phases of 4), cols c4..c4+3
    const int c4 = (lane & 63) * 4;          // 0..252 over 64 lanes? -> need 256/4=64 groups
    const int r0 = w * 8;

    f32x4_t acc[2][4];  // [mt][n]
#pragma unroll
    for (int m = 0; m < 2; ++m)
#pragma unroll
        for (int n = 0; n < 4; ++n) acc[m][n] = (f32x4_t){0.f, 0.f, 0.f, 0.f};

    float4 plg[2][4];    // [mt][ks*2+h]: prefetched logits runs
    float4 pf[2][4];     // [phase][row]: prefetched f rows

#define LOADT(tile_)                                                                     \
    {                                                                                    \
        const int lb_ = (tile_) * 64;                                                    \
        _Pragma("unroll")                                                                \
        for (int mt_ = 0; mt_ < 2; ++mt_) {                                              \
            const float* lg_ = mt_ ? lg1 : lg0;                                          \
            plg[mt_][0] = *(const float4*)(lg_ + lb_ + oct * 8);                         \
            plg[mt_][1] = *(const float4*)(lg_ + lb_ + oct * 8 + 4);                     \
            plg[mt_][2] = *(const float4*)(lg_ + lb_ + 32 + oct * 8);                    \
            plg[mt_][3] = *(const float4*)(lg_ + lb_ + 32 + oct * 8 + 4);                \
        }                                                                                \
        _Pragma("unroll")                                                                \
        for (int p_ = 0; p_ < 2; ++p_) {                                                 \
            _Pragma("unroll")                                                            \
            for (int i_ = 0; i_ < 4; ++i_)                                               \
                pf[p_][i_] = *(const float4*)(feats +                                    \
                    ((size_t)b * NL + lb_ + r0 + p_ * 4 + i_) * ND + d0 + c4);           \
        }                                                                                \
    }

    if (t0 < t1) LOADT(t0);

    for (int tile = t0; tile < t1; ++tile) {
        const int l0 = tile * 64;
        // ---- build A fragments in registers from plg (current tile)
        bf16x8 afH[2][2], afL[2][2];   // [mt][ks]
#pragma unroll
        for (int mt = 0; mt < 2; ++mt) {
            const float msk = mt ? ms1 : ms0;
#pragma unroll
            for (int ks = 0; ks < 2; ++ks) {
#pragma unroll
                for (int h = 0; h < 2; ++h) {
                    const float4 v = plg[mt][ks * 2 + h];
                    const int lbase = l0 + ks * 32 + oct * 8 + h * 4;
                    float av[4];
                    av[0] = (lbase + 0 < len) ? __expf(v.x - msk) : 0.f;
                    av[1] = (lbase + 1 < len) ? __expf(v.y - msk) : 0.f;
                    av[2] = (lbase + 2 < len) ? __expf(v.z - msk) : 0.f;
                    av[3] = (lbase + 3 < len) ? __expf(v.w - msk) : 0.f;
#pragma unroll
                    for (int c = 0; c < 4; ++c) {
                        const bf16_t hi = (bf16_t)av[c];
                        afH[mt][ks][h * 4 + c] = hi;
                        afL[mt][ks][h * 4 + c] = (bf16_t)(av[c] - (float)hi);
                    }
                }
            }
        }
        __syncthreads();   // all waves done reading fH of previous tile
        // ---- stage f^T (bf16) from pf: 4x4 register micro-transpose, 2 phases
#pragma unroll
        for (int p = 0; p < 2; ++p) {
            const int l4 = r0 + p * 4;
#pragma unroll
            for (int j = 0; j < 4; ++j) {
                const int d = c4 + j;
                bf16x4 hi;
                hi[0] = (bf16_t)(&pf[p][0].x)[j];
                hi[1] = (bf16_t)(&pf[p][1].x)[j];
                hi[2] = (bf16_t)(&pf[p][2].x)[j];
                hi[3] = (bf16_t)(&pf[p][3].x)[j];
                const int chunk = (l4 >> 3) ^ ((d ^ (d >> 3)) & 7);
                const int off = d * 128 + (chunk << 4) + (l4 & 7) * 2;
                *(bf16x4*)(fH + off) = hi;
            }
        }
        // ---- T14: issue next tile's loads (in flight across barrier + MFMA)
        if (tile + 1 < t1) LOADT(tile + 1);
        __syncthreads();   // fH ready
        // ---- MFMA: wave owns k in [kh*32, +32), d in [dh*64, +64)
#pragma unroll
        for (int ks = 0; ks < 2; ++ks) {
            const int cbase = ks * 4 + oct;  // chunk of contraction l = ks*32 + oct*8
            bf16x8 bfv[4];
#pragma unroll
            for (int n = 0; n < 4; ++n) {
                const int d = dh * 64 + n * 16 + lr;
                const int foff = d * 128 + ((cbase ^ ((d ^ (d >> 3)) & 7)) << 4);
                bfv[n] = *(const bf16x8*)(fH + foff);
            }
#pragma unroll
            for (int mt = 0; mt < 2; ++mt)
#pragma unroll
                for (int n = 0; n < 4; ++n) {
                    acc[mt][n] = __builtin_amdgcn_mfma_f32_16x16x32_bf16(afH[mt][ks], bfv[n], acc[mt][n], 0, 0, 0);
                    acc[mt][n] = __builtin_amdgcn_mfma_f32_16x16x32_bf16(afL[mt][ks], bfv[n], acc[mt][n], 0, 0, 0);
                }
        }
    }
#undef LOADT
    // write fp32 partials: pO[b][dc][s][k][DTILE]; C: row(m=k)=oct*4+r, col=lr
    float* po = pO + ((size_t)((b * 4 + dc) * S_SPLIT + s)) * (NK * DTILE);
#pragma unroll
    for (int mt = 0; mt < 2; ++mt)
#pragma unroll
        for (int n = 0; n < 4; ++n) {
#pragma unroll
            for (int r = 0; r < 4; ++r) {
                const int k = kh * 32 + mt * 16 + oct * 4 + r;
                po[k * DTILE + dh * 64 + n * 16 + lr] = acc[mt][n][r];
            }
        }
}

// ---------------- Kernel 4: sum S_SPLIT partials, subtract centroid, min over k
__global__ __launch_bounds__(128) void k_combine(const float* __restrict__ pO,
                                                 const float* __restrict__ centroids,
                                                 float* __restrict__ outun) {
    const int b = blockIdx.x >> 3;
    const int d = (blockIdx.x & 7) * 128 + threadIdx.x;  // 0..1023
    const int dc = d >> 8;
    const int dl = d & 255;
    const float* base = pO + ((size_t)(b * 4 + dc)) * S_SPLIT * NK * DTILE;
    float mn = 1e30f;
    for (int k = 0; k < NK; ++k) {
        float v = 0.f;
#pragma unroll
        for (int s = 0; s < S_SPLIT; ++s) v += base[(size_t)(s * NK + k) * DTILE + dl];
        v -= centroids[(size_t)k * ND + d];
        mn = fminf(mn, v);
    }
    outun[(size_t)b * ND + d] = mn;
}

// ---------------- Kernel 5: L2-normalize rows
__global__ __launch_bounds__(256) void k_norm(const float* __restrict__ outun,
                                              float* __restrict__ out) {
    const int b = blockIdx.x;
    const int t = threadIdx.x;
    float ss = 0.f;
    for (int d = t; d < ND; d += 256) {
        const float v = outun[(size_t)b * ND + d];
        ss += v * v;
    }
#pragma unroll
    for (int off = 32; off > 0; off >>= 1) ss += __shfl_down(ss, off);
    __shared__ float red[4];
    if ((t & 63) == 0) red[t >> 6] = ss;
    __syncthreads();
    const float tot = red[0] + red[1] + red[2] + red[3];
    const float inv = 1.0f / fmaxf(sqrtf(tot), 1e-12f);
    for (int d = t; d < ND; d += 256) out[(size_t)b * ND + d] = outun[(size_t)b * ND + d] * inv;
}

extern "C" void kernel_launch(void* const* d_in, const int* in_sizes, int n_in,
                              void* d_out, int out_size, void* d_ws, size_t ws_size,
                              hipStream_t stream) {
    const float* feats     = (const float*)d_in[0];
    const int*   lens      = (const int*)d_in[1];
    const float* W         = (const float*)d_in[2];
    const float* bias      = (const float*)d_in[3];
    const float* centroids = (const float*)d_in[4];
    float* out = (float*)d_out;

    char* ws = (char*)d_ws;
    size_t off = 0;
    bf16_t* Wb     = (bf16_t*)(ws + off); off += (size_t)NK * ND * sizeof(bf16_t);
    float* logitsT = (float*)(ws + off);  off += (size_t)NB * NL * NK * sizeof(float);
    float* pmax    = (float*)(ws + off);  off += (size_t)NB * 16 * NK * sizeof(float);
    float* psum    = (float*)(ws + off);  off += (size_t)NB * 16 * NK * sizeof(float);
    float* mbuf2   = (float*)(ws + off);  off += (size_t)NB * NK * sizeof(float);
    float* outun   = (float*)(ws + off);  off += (size_t)NB * ND * sizeof(float);
    float* pO      = (float*)(ws + off);  // 32*4*4*64*256*4 = 33.6 MB

    k_convw<<<NK * ND / 1024, 256, 0, stream>>>(W, Wb);
    k_logits<<<NB * (NL / 256), 256, 0, stream>>>(feats, Wb, bias, lens, logitsT, pmax, psum);
    k_sm2<<<NB, 64, 0, stream>>>(pmax, psum, lens, mbuf2);
    k_aggregate<<<NB * 4 * S_SPLIT, 512, 0, stream>>>(feats, logitsT, lens, mbuf2, pO);
    k_combine<<<NB * 8, 128, 0, stream>>>(pO, centroids, outun);
    k_norm<<<NB, 256, 0, stream>>>(outun, out);
}